// Round 11
// baseline (91.205 us; speedup 1.0000x reference)
//
#include <hip/hip_runtime.h>
#include <hip/hip_bf16.h>
#include <math.h>

#define B_ 4
#define I_ 48
#define J_ 384
#define DT_ 512
#define DM_ 80
#define DA_ 128
#define WIDTH_ 338          // J - I + 2
#define NEG (-1e30f)
#define LOG2E 1.4426950408889634f
#define LN2 0.6931471805599453f
#define LOGEPS2 (-1442.6950408889634f)   // -1000 * log2(e)
#define VPT 6               // positions per lane in the single-wave DP

typedef float f32x4 __attribute__((ext_vector_type(4)));

__device__ __forceinline__ float fexp2(float x) { return __builtin_amdgcn_exp2f(x); }
__device__ __forceinline__ float flog2(float x) { return __builtin_amdgcn_logf(x); }  // log2!

// DPP fetch with NEG fill (identity for LSE). 0x138=wave_shr:1 (lane t <- t-1),
// 0x130=wave_shl:1 (lane t <- t+1). Validated R3-R8.
template<int CTRL, int RMASK>
__device__ __forceinline__ float dppf(float x) {
    return __int_as_float(__builtin_amdgcn_update_dpp(
        __float_as_int(NEG), __float_as_int(x), CTRL, RMASK, 0xF, false));
}
__device__ __forceinline__ float rlane(float x, int l) {
    return __int_as_float(__builtin_amdgcn_readlane(__float_as_int(x), l));
}

// Branch-free LSE in log2 domain. NEG acts as -inf (exp2 flushes to 0).
__device__ __forceinline__ float lse2(float a, float b) {
    float m = fmaxf(a, b);
    float d = a - b;
    return m + flog2(1.0f + fexp2(-fabsf(d)));
}

// 64-lane inclusive forward LSE-scan, DPP only.
__device__ __forceinline__ float wave_scan_fwd(float x) {
    x = lse2(x, dppf<0x111, 0xF>(x));   // row_shr:1
    x = lse2(x, dppf<0x112, 0xF>(x));   // row_shr:2
    x = lse2(x, dppf<0x114, 0xF>(x));   // row_shr:4
    x = lse2(x, dppf<0x118, 0xF>(x));   // row_shr:8
    x = lse2(x, dppf<0x142, 0xA>(x));   // row_bcast15 -> rows 1,3
    x = lse2(x, dppf<0x143, 0xC>(x));   // row_bcast31 -> rows 2,3
    return x;
}
// 64-lane inclusive reverse (suffix) LSE-scan.
__device__ __forceinline__ float wave_scan_rev(float x, int lane) {
    x = lse2(x, dppf<0x101, 0xF>(x));   // row_shl:1
    x = lse2(x, dppf<0x102, 0xF>(x));
    x = lse2(x, dppf<0x104, 0xF>(x));
    x = lse2(x, dppf<0x108, 0xF>(x));
    float s16 = rlane(x, 16), s32 = rlane(x, 32), s48 = rlane(x, 48);
    float a  = lse2(s32, s48);
    float b2 = lse2(s16, a);
    int row = lane >> 4;
    float pre = (row == 0) ? b2 : (row == 1) ? a : (row == 2) ? s48 : NEG;
    return lse2(x, pre);
}

// fast tanh: t = exp2(2x*log2e); tanh = 1 - 2/(t+1). Inf/0 limits correct.
__device__ __forceinline__ float tanh_fast(float x) {
    float t = fexp2(x * (2.0f * LOG2E));
    return fmaf(-2.0f, __builtin_amdgcn_rcpf(t + 1.0f), 1.0f);
}

// ---------------- K1: projections pt = text@Wt ; pm = mel@Wm + bm ----------
__global__ __launch_bounds__(128) void proj_kernel(
        const float* __restrict__ text, const float* __restrict__ mel,
        const float* __restrict__ Wt, const float* __restrict__ Wm,
        const float* __restrict__ bm, float* __restrict__ pt, float* __restrict__ pm) {
    int blk = blockIdx.x;
    int d = threadIdx.x;
    __shared__ float sx[DT_];
    if (blk < B_ * I_) {
        const float* x = text + blk * DT_;
        for (int e = d; e < DT_; e += DA_) sx[e] = x[e];
        __syncthreads();
        float acc = 0.f;
        #pragma unroll 8
        for (int e = 0; e < DT_; ++e) acc += sx[e] * Wt[e * DA_ + d];
        pt[blk * DA_ + d] = acc;
    } else {
        int r = blk - B_ * I_;
        const float* x = mel + r * DM_;
        if (d < DM_) sx[d] = x[d];
        __syncthreads();
        float acc = bm[d];
        #pragma unroll 8
        for (int e = 0; e < DM_; ++e) acc += sx[e] * Wm[e * DA_ + d];
        pm[r * DA_ + d] = acc;
    }
}

// ---------------- K2: energy + rev-cum -> interleaved EZ[b,i][2j]={E,Z} ----
__global__ __launch_bounds__(384) void energy_kernel(
        const float* __restrict__ pt, const float* __restrict__ pm,
        const float* __restrict__ vw, const float* __restrict__ vb,
        const float* __restrict__ noise, float* __restrict__ EZ) {
    int bi = blockIdx.x;            // b*I + i
    int b = bi / I_, i = bi % I_;
    int t = threadIdx.x;            // j
    int w = t >> 6, lane = t & 63;
    __shared__ float sPt[DA_];
    __shared__ float sPR[8];
    __shared__ float sLast;
    if (t < DA_) sPt[t] = pt[bi * DA_ + t];
    __syncthreads();
    const float4* pmr4 = (const float4*)(pm + (size_t)(b * J_ + t) * DA_);
    float acc = 0.f;
    #pragma unroll 8
    for (int q = 0; q < DA_ / 4; ++q) {
        float4 v = pmr4[q];
        acc += vw[4 * q + 0] * tanh_fast(sPt[4 * q + 0] + v.x);
        acc += vw[4 * q + 1] * tanh_fast(sPt[4 * q + 1] + v.y);
        acc += vw[4 * q + 2] * tanh_fast(sPt[4 * q + 2] + v.z);
        acc += vw[4 * q + 3] * tanh_fast(sPt[4 * q + 3] + v.w);
    }
    float e = (acc + vb[0] + 2.0f * noise[bi * J_ + t]) * LOG2E;   // log2 domain

    float y = wave_scan_rev(e, lane);
    if (lane == 0) sPR[w] = y;
    if (t == J_ - 1) sLast = e;
    __syncthreads();
    float preR = NEG;
    #pragma unroll
    for (int ww = 1; ww < 6; ++ww) if (ww > w) preR = lse2(preR, sPR[ww]);
    float z = lse2(y, preR);
    if (i == I_ - 1) z = sLast;     // last text row: only j=J-1 valid
    float2 o; o.x = e; o.y = z;
    ((float2*)(EZ + (size_t)bi * J_ * 2))[t] = o;
}

// ---------------- soft row consumer (one wave; exact math, per R7) ---------
__device__ __noinline__ void soft_row_fn(const float* rB, const float* rZ,
                                         float* out, int lane, bool lastrow) {
    int p0 = lane * VPT;
    float Bv0 = rB[p0 + 0], Bv1 = rB[p0 + 1], Bv2 = rB[p0 + 2];
    float Bv3 = rB[p0 + 3], Bv4 = rB[p0 + 4], Bv5 = rB[p0 + 5];
    // local suffix (rev) scan on B
    float q23 = lse2(Bv2, Bv3), q45 = lse2(Bv4, Bv5);
    float g5 = Bv5, g4 = q45;
    float g3 = lse2(Bv3, q45), g2 = lse2(q23, q45);
    float g1 = lse2(Bv1, g2),  g0 = lse2(Bv0, g1);
    float Sg = wave_scan_rev(g0, lane);
    if (lastrow) {
        float tot = rlane(Sg, 0);               // LSE_k B[last,k]
        #pragma unroll
        for (int r = 0; r < VPT; ++r)
            out[p0 + r] = ((p0 + r == J_ - 1) ? tot : tot + LOGEPS2) * LN2;
        return;
    }
    float exG = dppf<0x130, 0xF>(Sg);           // incl suffix of next lane
    float Zv0 = rZ[p0 + 0], Zv1 = rZ[p0 + 1], Zv2 = rZ[p0 + 2];
    float Zv3 = rZ[p0 + 3], Zv4 = rZ[p0 + 4], Zv5 = rZ[p0 + 5];
    float C0 = Bv0 - Zv0, C1 = Bv1 - Zv1, C2 = Bv2 - Zv2;
    float C3 = Bv3 - Zv3, C4 = Bv4 - Zv4, C5 = Bv5 - Zv5;
    float s01 = lse2(C0, C1), p23 = lse2(C2, C3), p45 = lse2(C4, C5);
    float f0 = C0, f1 = s01, f2 = lse2(s01, C2), f3 = lse2(s01, p23);
    float f4 = lse2(f3, C4), f5 = lse2(f3, p45);
    float Sf = wave_scan_fwd(f5);
    float exF = dppf<0x138, 0xF>(Sf);           // prev lane's incl total
    // v[j] = lse2( Z[j] + cumIncl[j], revIncl[j+1] + LOGEPS2 )
    float o0 = lse2(Zv0 + lse2(f0, exF), lse2(g1, exG) + LOGEPS2);
    float o1 = lse2(Zv1 + lse2(f1, exF), lse2(g2, exG) + LOGEPS2);
    float o2 = lse2(Zv2 + lse2(f2, exF), lse2(g3, exG) + LOGEPS2);
    float o3 = lse2(Zv3 + lse2(f3, exF), lse2(g4, exG) + LOGEPS2);
    float o4 = lse2(Zv4 + lse2(f4, exF), lse2(g5, exG) + LOGEPS2);
    float o5 = lse2(Zv5 + lse2(f5, exF), exG + LOGEPS2);
    out[p0 + 0] = o0 * LN2; out[p0 + 1] = o1 * LN2; out[p0 + 2] = o2 * LN2;
    out[p0 + 3] = o3 * LN2; out[p0 + 4] = o4 * LN2; out[p0 + 5] = o5 * LN2;
}

// ---- dp-phase asm staging (validated R6-R8; vmcnt is per-wave, so the
// consumer waves' global stores do NOT perturb wave 0's counted waits) ------
#define WAITV_(n) asm volatile("s_waitcnt vmcnt(" #n ")" ::: "memory")
#define WAITV(n) do { WAITV_(n); __builtin_amdgcn_sched_barrier(0); } while (0)

#define LOAD3(S, rowexpr) do { \
    const float* _a = EZb + (size_t)(rowexpr) * (2 * J_) + t * 12; \
    asm volatile("global_load_dwordx4 %0, %3, off\n\t" \
                 "global_load_dwordx4 %1, %3, off offset:16\n\t" \
                 "global_load_dwordx4 %2, %3, off offset:32" \
                 : "=&v"(S##0), "=&v"(S##1), "=&v"(S##2) \
                 : "v"(_a) : "memory"); } while (0)

// No Bij stores: per body exactly 3 asm loads. Steady wait = 2 newer sets in
// flight = vmcnt(6); body47 (last, consumes row46 loaded at body44) = 3.
#define BODY(iexpr, NW, S, DOLOAD, lrow) do { \
    const int i_ = (iexpr); \
    WAITV(NW); \
    float e0 = S##0[0], z0 = S##0[1], e1 = S##0[2], z1 = S##0[3]; \
    float e2 = S##1[0], z2 = S##1[1], e3 = S##1[2], z3 = S##1[3]; \
    float e4 = S##2[0], z4 = S##2[1], e5 = S##2[2], z5 = S##2[3]; \
    if (DOLOAD) LOAD3(S, lrow); \
    ringZ[(i_ - 1) & 3][p0 + 0] = z0; ringZ[(i_ - 1) & 3][p0 + 1] = z1; \
    ringZ[(i_ - 1) & 3][p0 + 2] = z2; ringZ[(i_ - 1) & 3][p0 + 3] = z3; \
    ringZ[(i_ - 1) & 3][p0 + 4] = z4; ringZ[(i_ - 1) & 3][p0 + 5] = z5; \
    float D0 = prev[0] - z0, D1 = prev[1] - z1, D2 = prev[2] - z2; \
    float D3 = prev[3] - z3, D4 = prev[4] - z4, D5 = prev[5] - z5; \
    float s01 = lse2(D0, D1), p23 = lse2(D2, D3), p45 = lse2(D4, D5); \
    float f2 = lse2(s01, D2), f3 = lse2(s01, p23); \
    float f4 = lse2(f3, D4),  f5 = lse2(f3, p45); \
    float Sf  = wave_scan_fwd(f5); \
    float exF = dppf<0x138, 0xF>(Sf);      /* lane t-1 inclusive total */ \
    float flo = rlane(Sf, 63) + LOGEPS2;   /* total-approx floor (R7 bound) */ \
    float eP  = dppf<0x138, 0xF>(e5);      /* lane t-1's e5 = E[p0-1] */ \
    float v0 = lse2(eP + exF,            flo); \
    float v1 = lse2(e0 + lse2(D0,  exF), flo); \
    float v2 = lse2(e1 + lse2(s01, exF), flo); \
    float v3 = lse2(e2 + lse2(f2,  exF), flo); \
    float v4 = lse2(e3 + lse2(f3,  exF), flo); \
    float v5 = lse2(e4 + lse2(f4,  exF), flo); \
    int lo = i_, hi = i_ + WIDTH_; \
    prev[0] = (p0 + 0 >= lo && p0 + 0 < hi) ? v0 : NEG; \
    prev[1] = (p0 + 1 >= lo && p0 + 1 < hi) ? v1 : NEG; \
    prev[2] = (p0 + 2 >= lo && p0 + 2 < hi) ? v2 : NEG; \
    prev[3] = (p0 + 3 >= lo && p0 + 3 < hi) ? v3 : NEG; \
    prev[4] = (p0 + 4 >= lo && p0 + 4 < hi) ? v4 : NEG; \
    prev[5] = (p0 + 5 >= lo && p0 + 5 < hi) ? v5 : NEG; \
    ringB[i_ & 3][p0 + 0] = prev[0]; ringB[i_ & 3][p0 + 1] = prev[1]; \
    ringB[i_ & 3][p0 + 2] = prev[2]; ringB[i_ & 3][p0 + 3] = prev[3]; \
    ringB[i_ & 3][p0 + 4] = prev[4]; ringB[i_ & 3][p0 + 5] = prev[5]; \
} while (0)

// Round k: wave 0 runs DP body k (publishes ringB row k, ringZ row k-1);
// wave 1+((k-2)%5) consumes ring row k-2 -> soft. One barrier per round.
#define ROUND(iexpr, NW, S, DOLOAD, lrow) do { \
    if (t < 64) { BODY(iexpr, NW, S, DOLOAD, lrow); } \
    else { \
        int row_ = (iexpr) - 2; \
        if (row_ >= 0 && w == 1 + (row_ % 5)) \
            soft_row_fn(&ringB[row_ & 3][0], &ringZ[row_ & 3][0], \
                        softB + (size_t)row_ * J_, lane, false); \
    } \
    __syncthreads(); \
} while (0)

// ---------------- K3: banded DP + soft fused (4 blocks x 384) --------------
__global__ __launch_bounds__(384) void dpsoft_kernel(
        const float* __restrict__ EZ, float* __restrict__ soft) {
    int blk = blockIdx.x;
    int t = threadIdx.x;
    int w = t >> 6, lane = t & 63;
    int p0 = lane * VPT;
    const float* EZb = EZ + (size_t)blk * I_ * J_ * 2;
    float* softB = soft + (size_t)blk * I_ * J_;

    __shared__ float ringB[4][J_];
    __shared__ float ringZ[4][J_];

    float prev[VPT];
    f32x4 A0, A1, A2, B0, B1, B2, C0, C1, C2;

    if (t < 64) {
        #pragma unroll
        for (int r = 0; r < VPT; ++r) {
            prev[r] = (p0 + r == 0) ? 0.f : NEG;
            ringB[0][p0 + r] = prev[r];          // Bij row 0
        }
        LOAD3(A, 0); LOAD3(B, 1); LOAD3(C, 2);
    }
    // consumers first read ringB[0] at round 2 (after round 1's barrier)

    ROUND(1, 6, A, 1, 3);
    ROUND(2, 6, B, 1, 4);
    ROUND(3, 6, C, 1, 5);
    #pragma unroll 1
    for (int i = 4; i <= 43; i += 3) {
        ROUND(i,     6, A, 1, i + 2);
        ROUND(i + 1, 6, B, 1, i + 3);
        ROUND(i + 2, 6, C, 1, i + 4);   // i=43: body45 loads row 47 (unused, valid)
    }
    ROUND(46, 6, A, 0, 0);
    ROUND(47, 3, B, 0, 0);
    // drain rounds: soft rows 46, 47
    {
        int row_ = 46;                  // 46 % 5 = 1 -> wave 2
        if (t >= 64 && w == 1 + (row_ % 5))
            soft_row_fn(&ringB[row_ & 3][0], &ringZ[row_ & 3][0],
                        softB + (size_t)row_ * J_, lane, false);
        __syncthreads();
        row_ = 47;                      // 47 % 5 = 2 -> wave 3 (last row: no Z)
        if (t >= 64 && w == 1 + (row_ % 5))
            soft_row_fn(&ringB[row_ & 3][0], &ringB[row_ & 3][0],
                        softB + (size_t)row_ * J_, lane, true);
    }
}

// ---------------- K5: expanded[b,j,d] = sum_i exp(soft[b,i,j]) * text[b,i,d]
__global__ __launch_bounds__(512) void expand_kernel(
        const float* __restrict__ soft, const float* __restrict__ text,
        float* __restrict__ out) {
    int bj = blockIdx.x;
    int b = bj / J_, j = bj % J_;
    int d = threadIdx.x;
    __shared__ float p[I_];
    if (d < I_) p[d] = __expf(soft[(b * I_ + d) * J_ + j]);
    __syncthreads();
    float acc = 0.f;
    #pragma unroll
    for (int i = 0; i < I_; ++i) acc += p[i] * text[(b * I_ + i) * DT_ + d];
    out[bj * DT_ + d] = acc;
}

extern "C" void kernel_launch(void* const* d_in, const int* in_sizes, int n_in,
                              void* d_out, int out_size, void* d_ws, size_t ws_size,
                              hipStream_t stream) {
    const float* text  = (const float*)d_in[0];
    const float* mel   = (const float*)d_in[1];
    const float* noise = (const float*)d_in[2];
    const float* Wt    = (const float*)d_in[3];
    const float* Wm    = (const float*)d_in[4];
    const float* bm    = (const float*)d_in[5];
    const float* vw    = (const float*)d_in[6];
    const float* vb    = (const float*)d_in[7];
    // masks (d_in[8], d_in[9]) are all-true in this problem: tlen=I, mlen=J hardcoded.

    float* ws  = (float*)d_ws;
    float* EZ  = ws;                         // B*I*J*2 (interleaved E,Z; 16B aligned)
    float* pt  = EZ + B_ * I_ * J_ * 2;      // B*I*DA
    float* pm  = pt + B_ * I_ * DA_;         // B*J*DA

    float* soft     = (float*)d_out;             // B*I*J   (natural log)
    float* expanded = soft + B_ * I_ * J_;       // B*J*DT

    proj_kernel<<<B_ * (I_ + J_), 128, 0, stream>>>(text, mel, Wt, Wm, bm, pt, pm);
    energy_kernel<<<B_ * I_, 384, 0, stream>>>(pt, pm, vw, vb, noise, EZ);
    dpsoft_kernel<<<B_, 384, 0, stream>>>(EZ, soft);
    expand_kernel<<<B_ * J_, 512, 0, stream>>>(soft, text, expanded);
}

// Round 12
// 90.810 us; speedup vs baseline: 1.0044x; 1.0044x over previous
//
#include <hip/hip_runtime.h>
#include <hip/hip_bf16.h>
#include <math.h>

#define B_ 4
#define I_ 48
#define J_ 384
#define DT_ 512
#define DM_ 80
#define DA_ 128
#define WIDTH_ 338          // J - I + 2
#define NEG (-1e30f)
#define LOG2E 1.4426950408889634f
#define LN2 0.6931471805599453f
#define LOGEPS2 (-1442.6950408889634f)   // -1000 * log2(e)
#define VPT 6               // positions per lane in the single-wave DP

typedef float f32x4 __attribute__((ext_vector_type(4)));

__device__ __forceinline__ float fexp2(float x) { return __builtin_amdgcn_exp2f(x); }
__device__ __forceinline__ float flog2(float x) { return __builtin_amdgcn_logf(x); }  // log2!

// DPP fetch with NEG fill (identity for LSE). 0x138=wave_shr:1 (lane t <- t-1),
// 0x130=wave_shl:1 (lane t <- t+1). Validated R3-R10.
template<int CTRL, int RMASK>
__device__ __forceinline__ float dppf(float x) {
    return __int_as_float(__builtin_amdgcn_update_dpp(
        __float_as_int(NEG), __float_as_int(x), CTRL, RMASK, 0xF, false));
}
__device__ __forceinline__ float rlane(float x, int l) {
    return __int_as_float(__builtin_amdgcn_readlane(__float_as_int(x), l));
}

// Branch-free LSE in log2 domain. NEG acts as -inf (exp2 flushes to 0).
__device__ __forceinline__ float lse2(float a, float b) {
    float m = fmaxf(a, b);
    float d = a - b;
    return m + flog2(1.0f + fexp2(-fabsf(d)));
}

// 64-lane inclusive forward LSE-scan, DPP only.
__device__ __forceinline__ float wave_scan_fwd(float x) {
    x = lse2(x, dppf<0x111, 0xF>(x));   // row_shr:1
    x = lse2(x, dppf<0x112, 0xF>(x));   // row_shr:2
    x = lse2(x, dppf<0x114, 0xF>(x));   // row_shr:4
    x = lse2(x, dppf<0x118, 0xF>(x));   // row_shr:8
    x = lse2(x, dppf<0x142, 0xA>(x));   // row_bcast15 -> rows 1,3
    x = lse2(x, dppf<0x143, 0xC>(x));   // row_bcast31 -> rows 2,3
    return x;
}
// 64-lane inclusive reverse (suffix) LSE-scan.
__device__ __forceinline__ float wave_scan_rev(float x, int lane) {
    x = lse2(x, dppf<0x101, 0xF>(x));   // row_shl:1
    x = lse2(x, dppf<0x102, 0xF>(x));
    x = lse2(x, dppf<0x104, 0xF>(x));
    x = lse2(x, dppf<0x108, 0xF>(x));
    float s16 = rlane(x, 16), s32 = rlane(x, 32), s48 = rlane(x, 48);
    float a  = lse2(s32, s48);
    float b2 = lse2(s16, a);
    int row = lane >> 4;
    float pre = (row == 0) ? b2 : (row == 1) ? a : (row == 2) ? s48 : NEG;
    return lse2(x, pre);
}

// fast tanh: t = exp2(2x*log2e); tanh = 1 - 2/(t+1). Inf/0 limits correct.
__device__ __forceinline__ float tanh_fast(float x) {
    float t = fexp2(x * (2.0f * LOG2E));
    return fmaf(-2.0f, __builtin_amdgcn_rcpf(t + 1.0f), 1.0f);
}

// ---------------- K1: projections pt = text@Wt ; pm = mel@Wm + bm ----------
__global__ __launch_bounds__(128) void proj_kernel(
        const float* __restrict__ text, const float* __restrict__ mel,
        const float* __restrict__ Wt, const float* __restrict__ Wm,
        const float* __restrict__ bm, float* __restrict__ pt, float* __restrict__ pm) {
    int blk = blockIdx.x;
    int d = threadIdx.x;
    __shared__ float sx[DT_];
    if (blk < B_ * I_) {
        const float* x = text + blk * DT_;
        for (int e = d; e < DT_; e += DA_) sx[e] = x[e];
        __syncthreads();
        float acc = 0.f;
        #pragma unroll 8
        for (int e = 0; e < DT_; ++e) acc += sx[e] * Wt[e * DA_ + d];
        pt[blk * DA_ + d] = acc;
    } else {
        int r = blk - B_ * I_;
        const float* x = mel + r * DM_;
        if (d < DM_) sx[d] = x[d];
        __syncthreads();
        float acc = bm[d];
        #pragma unroll 8
        for (int e = 0; e < DM_; ++e) acc += sx[e] * Wm[e * DA_ + d];
        pm[r * DA_ + d] = acc;
    }
}

// ---------------- K2: energy + rev-cum -> interleaved EZ[b,i][2j]={E,Z} ----
__global__ __launch_bounds__(384) void energy_kernel(
        const float* __restrict__ pt, const float* __restrict__ pm,
        const float* __restrict__ vw, const float* __restrict__ vb,
        const float* __restrict__ noise, float* __restrict__ EZ) {
    int bi = blockIdx.x;            // b*I + i
    int b = bi / I_, i = bi % I_;
    int t = threadIdx.x;            // j
    int w = t >> 6, lane = t & 63;
    __shared__ float sPt[DA_];
    __shared__ float sPR[8];
    __shared__ float sLast;
    if (t < DA_) sPt[t] = pt[bi * DA_ + t];
    __syncthreads();
    const float4* pmr4 = (const float4*)(pm + (size_t)(b * J_ + t) * DA_);
    float acc = 0.f;
    #pragma unroll 8
    for (int q = 0; q < DA_ / 4; ++q) {
        float4 v = pmr4[q];
        acc += vw[4 * q + 0] * tanh_fast(sPt[4 * q + 0] + v.x);
        acc += vw[4 * q + 1] * tanh_fast(sPt[4 * q + 1] + v.y);
        acc += vw[4 * q + 2] * tanh_fast(sPt[4 * q + 2] + v.z);
        acc += vw[4 * q + 3] * tanh_fast(sPt[4 * q + 3] + v.w);
    }
    float e = (acc + vb[0] + 2.0f * noise[bi * J_ + t]) * LOG2E;   // log2 domain

    float y = wave_scan_rev(e, lane);
    if (lane == 0) sPR[w] = y;
    if (t == J_ - 1) sLast = e;
    __syncthreads();
    float preR = NEG;
    #pragma unroll
    for (int ww = 1; ww < 6; ++ww) if (ww > w) preR = lse2(preR, sPR[ww]);
    float z = lse2(y, preR);
    if (i == I_ - 1) z = sLast;     // last text row: only j=J-1 valid
    float2 o; o.x = e; o.y = z;
    ((float2*)(EZ + (size_t)bi * J_ * 2))[t] = o;
}

// ---------------- soft row consumer (one wave; exact math, per R7) ---------
__device__ __noinline__ void soft_row_fn(const float* rB, const float* rZ,
                                         float* out, int lane, bool lastrow) {
    int p0 = lane * VPT;
    float Bv0 = rB[p0 + 0], Bv1 = rB[p0 + 1], Bv2 = rB[p0 + 2];
    float Bv3 = rB[p0 + 3], Bv4 = rB[p0 + 4], Bv5 = rB[p0 + 5];
    // local suffix (rev) scan on B
    float q23 = lse2(Bv2, Bv3), q45 = lse2(Bv4, Bv5);
    float g5 = Bv5, g4 = q45;
    float g3 = lse2(Bv3, q45), g2 = lse2(q23, q45);
    float g1 = lse2(Bv1, g2),  g0 = lse2(Bv0, g1);
    float Sg = wave_scan_rev(g0, lane);
    if (lastrow) {
        float tot = rlane(Sg, 0);               // LSE_k B[last,k]
        #pragma unroll
        for (int r = 0; r < VPT; ++r)
            out[p0 + r] = ((p0 + r == J_ - 1) ? tot : tot + LOGEPS2) * LN2;
        return;
    }
    float exG = dppf<0x130, 0xF>(Sg);           // incl suffix of next lane
    float Zv0 = rZ[p0 + 0], Zv1 = rZ[p0 + 1], Zv2 = rZ[p0 + 2];
    float Zv3 = rZ[p0 + 3], Zv4 = rZ[p0 + 4], Zv5 = rZ[p0 + 5];
    float C0 = Bv0 - Zv0, C1 = Bv1 - Zv1, C2 = Bv2 - Zv2;
    float C3 = Bv3 - Zv3, C4 = Bv4 - Zv4, C5 = Bv5 - Zv5;
    float s01 = lse2(C0, C1), p23 = lse2(C2, C3), p45 = lse2(C4, C5);
    float f0 = C0, f1 = s01, f2 = lse2(s01, C2), f3 = lse2(s01, p23);
    float f4 = lse2(f3, C4), f5 = lse2(f3, p45);
    float Sf = wave_scan_fwd(f5);
    float exF = dppf<0x138, 0xF>(Sf);           // prev lane's incl total
    // v[j] = lse2( Z[j] + cumIncl[j], revIncl[j+1] + LOGEPS2 )
    float o0 = lse2(Zv0 + lse2(f0, exF), lse2(g1, exG) + LOGEPS2);
    float o1 = lse2(Zv1 + lse2(f1, exF), lse2(g2, exG) + LOGEPS2);
    float o2 = lse2(Zv2 + lse2(f2, exF), lse2(g3, exG) + LOGEPS2);
    float o3 = lse2(Zv3 + lse2(f3, exF), lse2(g4, exG) + LOGEPS2);
    float o4 = lse2(Zv4 + lse2(f4, exF), lse2(g5, exG) + LOGEPS2);
    float o5 = lse2(Zv5 + lse2(f5, exF), exG + LOGEPS2);
    out[p0 + 0] = o0 * LN2; out[p0 + 1] = o1 * LN2; out[p0 + 2] = o2 * LN2;
    out[p0 + 3] = o3 * LN2; out[p0 + 4] = o4 * LN2; out[p0 + 5] = o5 * LN2;
}

// ---- raw workgroup barrier: does NOT drain vmcnt (unlike __syncthreads,
// whose lowering emits s_waitcnt vmcnt(0) — the R10 regression). LDS
// visibility needs only lgkmcnt(0). "memory" clobbers + sched_barrier pin
// compiler motion on both sides. [HK technique (2), m139]
#define GBAR() do { \
    asm volatile("s_waitcnt lgkmcnt(0)" ::: "memory"); \
    __builtin_amdgcn_sched_barrier(0); \
    __builtin_amdgcn_s_barrier(); \
    asm volatile("" ::: "memory"); \
    __builtin_amdgcn_sched_barrier(0); \
} while (0)

// ---- dp-phase asm staging (validated R6-R10; vmcnt is per-wave) -----------
#define WAITV_(n) asm volatile("s_waitcnt vmcnt(" #n ")" ::: "memory")
#define WAITV(n) do { WAITV_(n); __builtin_amdgcn_sched_barrier(0); } while (0)

#define LOAD3(S, rowexpr) do { \
    const float* _a = EZb + (size_t)(rowexpr) * (2 * J_) + t * 12; \
    asm volatile("global_load_dwordx4 %0, %3, off\n\t" \
                 "global_load_dwordx4 %1, %3, off offset:16\n\t" \
                 "global_load_dwordx4 %2, %3, off offset:32" \
                 : "=&v"(S##0), "=&v"(S##1), "=&v"(S##2) \
                 : "v"(_a) : "memory"); } while (0)

// No global stores in BODY: per body exactly 3 asm loads (ring pub is LDS).
// Steady wait vmcnt(6) = 2 newer sets in flight (distance-3); last body 3.
#define BODY(iexpr, NW, S, DOLOAD, lrow) do { \
    const int i_ = (iexpr); \
    WAITV(NW); \
    float e0 = S##0[0], z0 = S##0[1], e1 = S##0[2], z1 = S##0[3]; \
    float e2 = S##1[0], z2 = S##1[1], e3 = S##1[2], z3 = S##1[3]; \
    float e4 = S##2[0], z4 = S##2[1], e5 = S##2[2], z5 = S##2[3]; \
    if (DOLOAD) LOAD3(S, lrow); \
    ringZ[(i_ - 1) & 3][p0 + 0] = z0; ringZ[(i_ - 1) & 3][p0 + 1] = z1; \
    ringZ[(i_ - 1) & 3][p0 + 2] = z2; ringZ[(i_ - 1) & 3][p0 + 3] = z3; \
    ringZ[(i_ - 1) & 3][p0 + 4] = z4; ringZ[(i_ - 1) & 3][p0 + 5] = z5; \
    float D0 = prev[0] - z0, D1 = prev[1] - z1, D2 = prev[2] - z2; \
    float D3 = prev[3] - z3, D4 = prev[4] - z4, D5 = prev[5] - z5; \
    float s01 = lse2(D0, D1), p23 = lse2(D2, D3), p45 = lse2(D4, D5); \
    float f2 = lse2(s01, D2), f3 = lse2(s01, p23); \
    float f4 = lse2(f3, D4),  f5 = lse2(f3, p45); \
    float Sf  = wave_scan_fwd(f5); \
    float exF = dppf<0x138, 0xF>(Sf);      /* lane t-1 inclusive total */ \
    float flo = rlane(Sf, 63) + LOGEPS2;   /* total-approx floor (R7 bound) */ \
    float eP  = dppf<0x138, 0xF>(e5);      /* lane t-1's e5 = E[p0-1] */ \
    float v0 = lse2(eP + exF,            flo); \
    float v1 = lse2(e0 + lse2(D0,  exF), flo); \
    float v2 = lse2(e1 + lse2(s01, exF), flo); \
    float v3 = lse2(e2 + lse2(f2,  exF), flo); \
    float v4 = lse2(e3 + lse2(f3,  exF), flo); \
    float v5 = lse2(e4 + lse2(f4,  exF), flo); \
    int lo = i_, hi = i_ + WIDTH_; \
    prev[0] = (p0 + 0 >= lo && p0 + 0 < hi) ? v0 : NEG; \
    prev[1] = (p0 + 1 >= lo && p0 + 1 < hi) ? v1 : NEG; \
    prev[2] = (p0 + 2 >= lo && p0 + 2 < hi) ? v2 : NEG; \
    prev[3] = (p0 + 3 >= lo && p0 + 3 < hi) ? v3 : NEG; \
    prev[4] = (p0 + 4 >= lo && p0 + 4 < hi) ? v4 : NEG; \
    prev[5] = (p0 + 5 >= lo && p0 + 5 < hi) ? v5 : NEG; \
    ringB[i_ & 3][p0 + 0] = prev[0]; ringB[i_ & 3][p0 + 1] = prev[1]; \
    ringB[i_ & 3][p0 + 2] = prev[2]; ringB[i_ & 3][p0 + 3] = prev[3]; \
    ringB[i_ & 3][p0 + 4] = prev[4]; ringB[i_ & 3][p0 + 5] = prev[5]; \
} while (0)

// Round k: wave 0 runs DP body k (publishes ringB row k, ringZ row k-1);
// wave 1+((k-2)%5) consumes ring row k-2 -> soft. One RAW barrier per round.
#define ROUND(iexpr, NW, S, DOLOAD, lrow) do { \
    if (t < 64) { BODY(iexpr, NW, S, DOLOAD, lrow); } \
    else { \
        int row_ = (iexpr) - 2; \
        if (row_ >= 0 && w == 1 + (row_ % 5)) \
            soft_row_fn(&ringB[row_ & 3][0], &ringZ[row_ & 3][0], \
                        softB + (size_t)row_ * J_, lane, false); \
    } \
    GBAR(); \
} while (0)

// ---------------- K3: banded DP + soft fused (4 blocks x 384) --------------
__global__ __launch_bounds__(384) void dpsoft_kernel(
        const float* __restrict__ EZ, float* __restrict__ soft) {
    int blk = blockIdx.x;
    int t = threadIdx.x;
    int w = t >> 6, lane = t & 63;
    int p0 = lane * VPT;
    const float* EZb = EZ + (size_t)blk * I_ * J_ * 2;
    float* softB = soft + (size_t)blk * I_ * J_;

    __shared__ float ringB[4][J_];
    __shared__ float ringZ[4][J_];

    float prev[VPT];
    f32x4 A0, A1, A2, B0, B1, B2, C0, C1, C2;

    if (t < 64) {
        #pragma unroll
        for (int r = 0; r < VPT; ++r) {
            prev[r] = (p0 + r == 0) ? 0.f : NEG;
            ringB[0][p0 + r] = prev[r];          // Bij row 0
        }
        LOAD3(A, 0); LOAD3(B, 1); LOAD3(C, 2);
    }
    // consumers first read ringB[0]/ringZ[0] at round 2 (after round-1 barrier)

    ROUND(1, 6, A, 1, 3);
    ROUND(2, 6, B, 1, 4);
    ROUND(3, 6, C, 1, 5);
    #pragma unroll 1
    for (int i = 4; i <= 43; i += 3) {
        ROUND(i,     6, A, 1, i + 2);
        ROUND(i + 1, 6, B, 1, i + 3);
        ROUND(i + 2, 6, C, 1, i + 4);   // i=43: body45 loads row 47 (unused, valid)
    }
    ROUND(46, 6, A, 0, 0);
    ROUND(47, 3, B, 0, 0);
    // drain: soft rows 46 (wave 2) and 47 (wave 3) — disjoint slots/outputs,
    // both written before the round-47 barrier; run concurrently.
    {
        int row_ = 46;
        if (t >= 64 && w == 1 + (row_ % 5))
            soft_row_fn(&ringB[row_ & 3][0], &ringZ[row_ & 3][0],
                        softB + (size_t)row_ * J_, lane, false);
        row_ = 47;
        if (t >= 64 && w == 1 + (row_ % 5))
            soft_row_fn(&ringB[row_ & 3][0], &ringB[row_ & 3][0],
                        softB + (size_t)row_ * J_, lane, true);
    }
}

// ---------------- K5: expanded[b,j,d] = sum_i exp(soft[b,i,j]) * text[b,i,d]
__global__ __launch_bounds__(512) void expand_kernel(
        const float* __restrict__ soft, const float* __restrict__ text,
        float* __restrict__ out) {
    int bj = blockIdx.x;
    int b = bj / J_, j = bj % J_;
    int d = threadIdx.x;
    __shared__ float p[I_];
    if (d < I_) p[d] = __expf(soft[(b * I_ + d) * J_ + j]);
    __syncthreads();
    float acc = 0.f;
    #pragma unroll
    for (int i = 0; i < I_; ++i) acc += p[i] * text[(b * I_ + i) * DT_ + d];
    out[bj * DT_ + d] = acc;
}

extern "C" void kernel_launch(void* const* d_in, const int* in_sizes, int n_in,
                              void* d_out, int out_size, void* d_ws, size_t ws_size,
                              hipStream_t stream) {
    const float* text  = (const float*)d_in[0];
    const float* mel   = (const float*)d_in[1];
    const float* noise = (const float*)d_in[2];
    const float* Wt    = (const float*)d_in[3];
    const float* Wm    = (const float*)d_in[4];
    const float* bm    = (const float*)d_in[5];
    const float* vw    = (const float*)d_in[6];
    const float* vb    = (const float*)d_in[7];
    // masks (d_in[8], d_in[9]) are all-true in this problem: tlen=I, mlen=J hardcoded.

    float* ws  = (float*)d_ws;
    float* EZ  = ws;                         // B*I*J*2 (interleaved E,Z; 16B aligned)
    float* pt  = EZ + B_ * I_ * J_ * 2;      // B*I*DA
    float* pm  = pt + B_ * I_ * DA_;         // B*J*DA

    float* soft     = (float*)d_out;             // B*I*J   (natural log)
    float* expanded = soft + B_ * I_ * J_;       // B*J*DT

    proj_kernel<<<B_ * (I_ + J_), 128, 0, stream>>>(text, mel, Wt, Wm, bm, pt, pm);
    energy_kernel<<<B_ * I_, 384, 0, stream>>>(pt, pm, vw, vb, noise, EZ);
    dpsoft_kernel<<<B_, 384, 0, stream>>>(EZ, soft);
    expand_kernel<<<B_ * J_, 512, 0, stream>>>(soft, text, expanded);
}

// Round 13
// 71.801 us; speedup vs baseline: 1.2703x; 1.2647x over previous
//
#include <hip/hip_runtime.h>
#include <hip/hip_bf16.h>
#include <math.h>

#define B_ 4
#define I_ 48
#define J_ 384
#define DT_ 512
#define DM_ 80
#define DA_ 128
#define WIDTH_ 338          // J - I + 2
#define NEG (-1e30f)
#define LOG2E 1.4426950408889634f
#define LN2 0.6931471805599453f
#define LOGEPS2 (-1442.6950408889634f)   // -1000 * log2(e)
#define VPT 6               // positions per lane in the single-wave DP

typedef float f32x4 __attribute__((ext_vector_type(4)));
typedef float f32x2 __attribute__((ext_vector_type(2)));

__device__ __forceinline__ float fexp2(float x) { return __builtin_amdgcn_exp2f(x); }
__device__ __forceinline__ float flog2(float x) { return __builtin_amdgcn_logf(x); }  // log2!

// DPP fetch with NEG fill (identity for LSE). 0x138=wave_shr:1 (lane t <- t-1),
// 0x130=wave_shl:1 (lane t <- t+1). Validated R3-R12.
template<int CTRL, int RMASK>
__device__ __forceinline__ float dppf(float x) {
    return __int_as_float(__builtin_amdgcn_update_dpp(
        __float_as_int(NEG), __float_as_int(x), CTRL, RMASK, 0xF, false));
}
__device__ __forceinline__ float rlane(float x, int l) {
    return __int_as_float(__builtin_amdgcn_readlane(__float_as_int(x), l));
}

// Branch-free LSE in log2 domain. NEG acts as -inf (exp2 flushes to 0).
__device__ __forceinline__ float lse2(float a, float b) {
    float m = fmaxf(a, b);
    float d = a - b;
    return m + flog2(1.0f + fexp2(-fabsf(d)));
}

// 64-lane inclusive forward LSE-scan, DPP only.
__device__ __forceinline__ float wave_scan_fwd(float x) {
    x = lse2(x, dppf<0x111, 0xF>(x));   // row_shr:1
    x = lse2(x, dppf<0x112, 0xF>(x));   // row_shr:2
    x = lse2(x, dppf<0x114, 0xF>(x));   // row_shr:4
    x = lse2(x, dppf<0x118, 0xF>(x));   // row_shr:8
    x = lse2(x, dppf<0x142, 0xA>(x));   // row_bcast15 -> rows 1,3
    x = lse2(x, dppf<0x143, 0xC>(x));   // row_bcast31 -> rows 2,3
    return x;
}
// 64-lane inclusive reverse (suffix) LSE-scan.
__device__ __forceinline__ float wave_scan_rev(float x, int lane) {
    x = lse2(x, dppf<0x101, 0xF>(x));   // row_shl:1
    x = lse2(x, dppf<0x102, 0xF>(x));
    x = lse2(x, dppf<0x104, 0xF>(x));
    x = lse2(x, dppf<0x108, 0xF>(x));
    float s16 = rlane(x, 16), s32 = rlane(x, 32), s48 = rlane(x, 48);
    float a  = lse2(s32, s48);
    float b2 = lse2(s16, a);
    int row = lane >> 4;
    float pre = (row == 0) ? b2 : (row == 1) ? a : (row == 2) ? s48 : NEG;
    return lse2(x, pre);
}

// fast tanh: t = exp2(2x*log2e); tanh = 1 - 2/(t+1). Inf/0 limits correct.
__device__ __forceinline__ float tanh_fast(float x) {
    float t = fexp2(x * (2.0f * LOG2E));
    return fmaf(-2.0f, __builtin_amdgcn_rcpf(t + 1.0f), 1.0f);
}

// ---------------- K1: projections pt = text@Wt ; pm = mel@Wm + bm ----------
__global__ __launch_bounds__(128) void proj_kernel(
        const float* __restrict__ text, const float* __restrict__ mel,
        const float* __restrict__ Wt, const float* __restrict__ Wm,
        const float* __restrict__ bm, float* __restrict__ pt, float* __restrict__ pm) {
    int blk = blockIdx.x;
    int d = threadIdx.x;
    __shared__ float sx[DT_];
    if (blk < B_ * I_) {
        const float* x = text + blk * DT_;
        for (int e = d; e < DT_; e += DA_) sx[e] = x[e];
        __syncthreads();
        float acc = 0.f;
        #pragma unroll 8
        for (int e = 0; e < DT_; ++e) acc += sx[e] * Wt[e * DA_ + d];
        pt[blk * DA_ + d] = acc;
    } else {
        int r = blk - B_ * I_;
        const float* x = mel + r * DM_;
        if (d < DM_) sx[d] = x[d];
        __syncthreads();
        float acc = bm[d];
        #pragma unroll 8
        for (int e = 0; e < DM_; ++e) acc += sx[e] * Wm[e * DA_ + d];
        pm[r * DA_ + d] = acc;
    }
}

// ---------------- K2: energy + rev-cum -> interleaved EZ[b,i][2j]={E,Z} ----
__global__ __launch_bounds__(384) void energy_kernel(
        const float* __restrict__ pt, const float* __restrict__ pm,
        const float* __restrict__ vw, const float* __restrict__ vb,
        const float* __restrict__ noise, float* __restrict__ EZ) {
    int bi = blockIdx.x;            // b*I + i
    int b = bi / I_, i = bi % I_;
    int t = threadIdx.x;            // j
    int w = t >> 6, lane = t & 63;
    __shared__ float sPt[DA_];
    __shared__ float sPR[8];
    __shared__ float sLast;
    if (t < DA_) sPt[t] = pt[bi * DA_ + t];
    __syncthreads();
    const float4* pmr4 = (const float4*)(pm + (size_t)(b * J_ + t) * DA_);
    float acc = 0.f;
    #pragma unroll 8
    for (int q = 0; q < DA_ / 4; ++q) {
        float4 v = pmr4[q];
        acc += vw[4 * q + 0] * tanh_fast(sPt[4 * q + 0] + v.x);
        acc += vw[4 * q + 1] * tanh_fast(sPt[4 * q + 1] + v.y);
        acc += vw[4 * q + 2] * tanh_fast(sPt[4 * q + 2] + v.z);
        acc += vw[4 * q + 3] * tanh_fast(sPt[4 * q + 3] + v.w);
    }
    float e = (acc + vb[0] + 2.0f * noise[bi * J_ + t]) * LOG2E;   // log2 domain

    float y = wave_scan_rev(e, lane);
    if (lane == 0) sPR[w] = y;
    if (t == J_ - 1) sLast = e;
    __syncthreads();
    float preR = NEG;
    #pragma unroll
    for (int ww = 1; ww < 6; ++ww) if (ww > w) preR = lse2(preR, sPR[ww]);
    float z = lse2(y, preR);
    if (i == I_ - 1) z = sLast;     // last text row: only j=J-1 valid
    float2 o; o.x = e; o.y = z;
    ((float2*)(EZ + (size_t)bi * J_ * 2))[t] = o;
}

// ---- dp-phase asm staging (R7-validated: dist-3, counted waits, floor) ----
#define WAITV_(n) asm volatile("s_waitcnt vmcnt(" #n ")" ::: "memory")
#define WAITV(n) do { WAITV_(n); __builtin_amdgcn_sched_barrier(0); } while (0)

#define LOAD3(S, rowexpr) do { \
    const float* _a = EZb + (size_t)(rowexpr) * (2 * J_) + t * 12; \
    asm volatile("global_load_dwordx4 %0, %3, off\n\t" \
                 "global_load_dwordx4 %1, %3, off offset:16\n\t" \
                 "global_load_dwordx4 %2, %3, off offset:32" \
                 : "=&v"(S##0), "=&v"(S##1), "=&v"(S##2) \
                 : "v"(_a) : "memory"); } while (0)

#define STORE42(addr, q, dd) \
    asm volatile("global_store_dwordx4 %2, %0, off\n\t" \
                 "global_store_dwordx2 %2, %1, off offset:16" \
                 :: "v"(q), "v"(dd), "v"(addr) : "memory")

#define BODY(iexpr, NW, S, DOLOAD, lrow) do { \
    const int i_ = (iexpr); \
    WAITV(NW); \
    float e0 = S##0[0], z0 = S##0[1], e1 = S##0[2], z1 = S##0[3]; \
    float e2 = S##1[0], z2 = S##1[1], e3 = S##1[2], z3 = S##1[3]; \
    float e4 = S##2[0], z4 = S##2[1], e5 = S##2[2], z5 = S##2[3]; \
    if (DOLOAD) LOAD3(S, lrow); \
    float D0 = prev[0] - z0, D1 = prev[1] - z1, D2 = prev[2] - z2; \
    float D3 = prev[3] - z3, D4 = prev[4] - z4, D5 = prev[5] - z5; \
    float s01 = lse2(D0, D1), p23 = lse2(D2, D3), p45 = lse2(D4, D5); \
    float f2 = lse2(s01, D2), f3 = lse2(s01, p23); \
    float f4 = lse2(f3, D4),  f5 = lse2(f3, p45); \
    float Sf  = wave_scan_fwd(f5); \
    float exF = dppf<0x138, 0xF>(Sf);      /* lane t-1 inclusive total */ \
    float flo = rlane(Sf, 63) + LOGEPS2;   /* total-approx floor (R7 bound) */ \
    float eP  = dppf<0x138, 0xF>(e5);      /* lane t-1's e5 = E[p0-1] */ \
    float v0 = lse2(eP + exF,            flo); \
    float v1 = lse2(e0 + lse2(D0,  exF), flo); \
    float v2 = lse2(e1 + lse2(s01, exF), flo); \
    float v3 = lse2(e2 + lse2(f2,  exF), flo); \
    float v4 = lse2(e3 + lse2(f3,  exF), flo); \
    float v5 = lse2(e4 + lse2(f4,  exF), flo); \
    int lo = i_, hi = i_ + WIDTH_; \
    prev[0] = (p0 + 0 >= lo && p0 + 0 < hi) ? v0 : NEG; \
    prev[1] = (p0 + 1 >= lo && p0 + 1 < hi) ? v1 : NEG; \
    prev[2] = (p0 + 2 >= lo && p0 + 2 < hi) ? v2 : NEG; \
    prev[3] = (p0 + 3 >= lo && p0 + 3 < hi) ? v3 : NEG; \
    prev[4] = (p0 + 4 >= lo && p0 + 4 < hi) ? v4 : NEG; \
    prev[5] = (p0 + 5 >= lo && p0 + 5 < hi) ? v5 : NEG; \
    { f32x4 q = {prev[0], prev[1], prev[2], prev[3]}; \
      f32x2 dd = {prev[4], prev[5]}; \
      float* _ba = Bb + i_ * J_ + p0; \
      STORE42(_ba, q, dd); } \
} while (0)

// ---------------- K3: DP (wave 0) -> one barrier -> soft (6 waves) ---------
__global__ __launch_bounds__(384) void dpsoft_kernel(
        const float* __restrict__ EZ, float* __restrict__ Bij,
        float* __restrict__ soft) {
    int blk = blockIdx.x;
    int t = threadIdx.x;
    int w = t >> 6, lane = t & 63;
    const float* EZb = EZ + (size_t)blk * I_ * J_ * 2;
    float* Bb = Bij + (size_t)blk * I_ * J_;
    float* softB = soft + (size_t)blk * I_ * J_;

    // ---- DP phase: wave 0 only (R7-validated kernel body, verbatim) ----
    if (t < 64) {
        int p0 = t * VPT;
        float prev[VPT];
        #pragma unroll
        for (int r = 0; r < VPT; ++r) prev[r] = (p0 + r == 0) ? 0.f : NEG;

        { f32x4 q = {prev[0], prev[1], prev[2], prev[3]};
          f32x2 dd = {prev[4], prev[5]};
          float* _ba = Bb + p0;
          STORE42(_ba, q, dd); }

        f32x4 A0, A1, A2, B0, B1, B2, C0, C1, C2;
        LOAD3(A, 0); LOAD3(B, 1); LOAD3(C, 2);

        BODY(1, 6,  A, 1, 3);
        BODY(2, 8,  B, 1, 4);
        BODY(3, 10, C, 1, 5);
        #pragma unroll 1
        for (int i = 4; i <= 43; i += 3) {
            BODY(i,     12, A, 1, i + 2);
            BODY(i + 1, 12, B, 1, i + 3);
            BODY(i + 2, 12, C, 1, i + 4);  // i=43: body45 loads row 47 (unused, valid)
        }
        BODY(46, 12, A, 0, 0);
        BODY(47, 9,  B, 0, 0);
    }
    // One full barrier: __syncthreads' vmcnt(0) drain flushes wave 0's Bij
    // stores to L2; L1 was invalidated at launch and Bij was not read before,
    // so post-barrier reads are coherent (same pattern as the R7 cross-kernel
    // handoff, now intra-kernel).
    __syncthreads();

    // ---- soft phase: 6 waves x 8 rows each, exact math (R7 soft) ----
    int p0 = lane * VPT;
    #pragma unroll 1
    for (int rr = 0; rr < 8; ++rr) {
        int row = w * 8 + rr;
        const float* Brow = Bb + (size_t)row * J_;
        float Bv0 = Brow[p0 + 0], Bv1 = Brow[p0 + 1], Bv2 = Brow[p0 + 2];
        float Bv3 = Brow[p0 + 3], Bv4 = Brow[p0 + 4], Bv5 = Brow[p0 + 5];
        // local suffix (rev) scan on B
        float q23 = lse2(Bv2, Bv3), q45 = lse2(Bv4, Bv5);
        float g5 = Bv5, g4 = q45;
        float g3 = lse2(Bv3, q45), g2 = lse2(q23, q45);
        float g1 = lse2(Bv1, g2),  g0 = lse2(Bv0, g1);
        float Sg = wave_scan_rev(g0, lane);
        float* orow = softB + (size_t)row * J_ + p0;
        if (row == I_ - 1) {
            float tot = rlane(Sg, 0);               // LSE_k B[last,k]
            #pragma unroll
            for (int r = 0; r < VPT; ++r)
                orow[r] = ((p0 + r == J_ - 1) ? tot : tot + LOGEPS2) * LN2;
        } else {
            float exG = dppf<0x130, 0xF>(Sg);       // incl suffix of next lane
            const float* Erow = EZb + (size_t)row * 2 * J_;
            float Zv0 = Erow[(p0 + 0) * 2 + 1], Zv1 = Erow[(p0 + 1) * 2 + 1];
            float Zv2 = Erow[(p0 + 2) * 2 + 1], Zv3 = Erow[(p0 + 3) * 2 + 1];
            float Zv4 = Erow[(p0 + 4) * 2 + 1], Zv5 = Erow[(p0 + 5) * 2 + 1];
            float C0 = Bv0 - Zv0, C1 = Bv1 - Zv1, C2 = Bv2 - Zv2;
            float C3 = Bv3 - Zv3, C4 = Bv4 - Zv4, C5 = Bv5 - Zv5;
            float s01 = lse2(C0, C1), p23 = lse2(C2, C3), p45 = lse2(C4, C5);
            float f0 = C0, f1 = s01, f2 = lse2(s01, C2), f3 = lse2(s01, p23);
            float f4 = lse2(f3, C4), f5 = lse2(f3, p45);
            float Sf = wave_scan_fwd(f5);
            float exF = dppf<0x138, 0xF>(Sf);       // prev lane's incl total
            float o0 = lse2(Zv0 + lse2(f0, exF), lse2(g1, exG) + LOGEPS2);
            float o1 = lse2(Zv1 + lse2(f1, exF), lse2(g2, exG) + LOGEPS2);
            float o2 = lse2(Zv2 + lse2(f2, exF), lse2(g3, exG) + LOGEPS2);
            float o3 = lse2(Zv3 + lse2(f3, exF), lse2(g4, exG) + LOGEPS2);
            float o4 = lse2(Zv4 + lse2(f4, exF), lse2(g5, exG) + LOGEPS2);
            float o5 = lse2(Zv5 + lse2(f5, exF), exG + LOGEPS2);
            orow[0] = o0 * LN2; orow[1] = o1 * LN2; orow[2] = o2 * LN2;
            orow[3] = o3 * LN2; orow[4] = o4 * LN2; orow[5] = o5 * LN2;
        }
    }
}

// ---------------- K5: expanded[b,j,d] = sum_i exp(soft[b,i,j]) * text[b,i,d]
__global__ __launch_bounds__(512) void expand_kernel(
        const float* __restrict__ soft, const float* __restrict__ text,
        float* __restrict__ out) {
    int bj = blockIdx.x;
    int b = bj / J_, j = bj % J_;
    int d = threadIdx.x;
    __shared__ float p[I_];
    if (d < I_) p[d] = __expf(soft[(b * I_ + d) * J_ + j]);
    __syncthreads();
    float acc = 0.f;
    #pragma unroll
    for (int i = 0; i < I_; ++i) acc += p[i] * text[(b * I_ + i) * DT_ + d];
    out[bj * DT_ + d] = acc;
}

extern "C" void kernel_launch(void* const* d_in, const int* in_sizes, int n_in,
                              void* d_out, int out_size, void* d_ws, size_t ws_size,
                              hipStream_t stream) {
    const float* text  = (const float*)d_in[0];
    const float* mel   = (const float*)d_in[1];
    const float* noise = (const float*)d_in[2];
    const float* Wt    = (const float*)d_in[3];
    const float* Wm    = (const float*)d_in[4];
    const float* bm    = (const float*)d_in[5];
    const float* vw    = (const float*)d_in[6];
    const float* vb    = (const float*)d_in[7];
    // masks (d_in[8], d_in[9]) are all-true in this problem: tlen=I, mlen=J hardcoded.

    float* ws  = (float*)d_ws;
    float* EZ  = ws;                         // B*I*J*2 (interleaved E,Z; 16B aligned)
    float* pt  = EZ + B_ * I_ * J_ * 2;      // B*I*DA
    float* pm  = pt + B_ * I_ * DA_;         // B*J*DA
    float* Bij = pm + B_ * J_ * DA_;         // B*I*J   (log2 domain)

    float* soft     = (float*)d_out;             // B*I*J   (natural log)
    float* expanded = soft + B_ * I_ * J_;       // B*J*DT

    proj_kernel<<<B_ * (I_ + J_), 128, 0, stream>>>(text, mel, Wt, Wm, bm, pt, pm);
    energy_kernel<<<B_ * I_, 384, 0, stream>>>(pt, pm, vw, vb, noise, EZ);
    dpsoft_kernel<<<B_, 384, 0, stream>>>(EZ, Bij, soft);
    expand_kernel<<<B_ * J_, 512, 0, stream>>>(soft, text, expanded);
}